// Round 1
// baseline (463.506 us; speedup 1.0000x reference)
//
#include <hip/hip_runtime.h>

#define N_SRC_N  100000
#define N_DST_N  50000
#define NE       1000000
#define IN_F     256
#define NH       4
#define ND       32
#define HD       128   // NH*ND
#define NEG_SLOPE 0.2f

// ---------------- GEMM: h = x @ w^T  (x:[N,256] fp32, w:[128,256] fp32, h:[N,128]) ----
#define BM 128
#define BK 32

__global__ __launch_bounds__(256) void gemm_fc(
    const float* __restrict__ x, const float* __restrict__ w,
    float* __restrict__ h, int nrows)
{
    __shared__ float xs[BK][BM + 4];    // [k][row], transposed for b128 frag reads
    __shared__ float wsh[BK][HD + 4];   // [k][col]

    const int tid = threadIdx.x;
    const int ty = tid >> 4;    // 0..15
    const int tx = tid & 15;    // 0..15
    const int row0 = blockIdx.x * BM;

    float acc[8][8];
#pragma unroll
    for (int i = 0; i < 8; ++i)
#pragma unroll
        for (int j = 0; j < 8; ++j) acc[i][j] = 0.f;

    const int lr = tid >> 1;          // 0..127: row (x) / col (w) for staging
    const int lk = (tid & 1) * 16;    // 0 or 16

    for (int kt = 0; kt < IN_F; kt += BK) {
        // stage x chunk (transposed)
        if (row0 + lr < nrows) {
            const float* p = x + (size_t)(row0 + lr) * IN_F + kt + lk;
#pragma unroll
            for (int q = 0; q < 4; ++q) {
                float4 v = *(const float4*)(p + q * 4);
                xs[lk + q*4 + 0][lr] = v.x;
                xs[lk + q*4 + 1][lr] = v.y;
                xs[lk + q*4 + 2][lr] = v.z;
                xs[lk + q*4 + 3][lr] = v.w;
            }
        }
        // stage w chunk (transposed)
        {
            const float* p = w + (size_t)lr * IN_F + kt + lk;
#pragma unroll
            for (int q = 0; q < 4; ++q) {
                float4 v = *(const float4*)(p + q * 4);
                wsh[lk + q*4 + 0][lr] = v.x;
                wsh[lk + q*4 + 1][lr] = v.y;
                wsh[lk + q*4 + 2][lr] = v.z;
                wsh[lk + q*4 + 3][lr] = v.w;
            }
        }
        __syncthreads();
#pragma unroll 8
        for (int k = 0; k < BK; ++k) {
            float a[8], b[8];
            *(float4*)&a[0] = *(const float4*)&xs[k][ty * 8];
            *(float4*)&a[4] = *(const float4*)&xs[k][ty * 8 + 4];
            *(float4*)&b[0] = *(const float4*)&wsh[k][tx * 8];
            *(float4*)&b[4] = *(const float4*)&wsh[k][tx * 8 + 4];
#pragma unroll
            for (int i = 0; i < 8; ++i)
#pragma unroll
                for (int j = 0; j < 8; ++j)
                    acc[i][j] = fmaf(a[i], b[j], acc[i][j]);
        }
        __syncthreads();
    }

#pragma unroll
    for (int i = 0; i < 8; ++i) {
        int row = row0 + ty * 8 + i;
        if (row < nrows) {
            float4 v0 = make_float4(acc[i][0], acc[i][1], acc[i][2], acc[i][3]);
            float4 v1 = make_float4(acc[i][4], acc[i][5], acc[i][6], acc[i][7]);
            *(float4*)&h[(size_t)row * HD + tx * 8]     = v0;
            *(float4*)&h[(size_t)row * HD + tx * 8 + 4] = v1;
        }
    }
}

// ------------- el[n,h] = <h[n,h,:], al[h,:]> ; er[i,h] = <h[dnid[i],h,:], ar[h,:]> ----
__global__ __launch_bounds__(256) void attn_scalars(
    const float* __restrict__ h, const float* __restrict__ al, const float* __restrict__ ar,
    const int* __restrict__ dnid, float* __restrict__ el, float* __restrict__ er,
    int nsrc, int ndst)
{
    int job = blockIdx.x * 2 + (threadIdx.x >> 7);   // 2 rows per 256-thread block
    int c = threadIdx.x & 127;                       // 0..127
    int head = c >> 5;

    if (job < nsrc) {
        float v = h[(size_t)job * HD + c] * al[c];
#pragma unroll
        for (int o = 16; o > 0; o >>= 1) v += __shfl_xor(v, o, 32);
        if ((c & 31) == 0) el[job * NH + head] = v;
    } else {
        int i = job - nsrc;
        if (i < ndst) {
            int n = dnid[i];
            float v = h[(size_t)n * HD + c] * ar[c];
#pragma unroll
            for (int o = 16; o > 0; o >>= 1) v += __shfl_xor(v, o, 32);
            if ((c & 31) == 0) er[i * NH + head] = v;
        }
    }
}

// ---------------- CSR build --------------------------------------------------------
__global__ void hist_kernel(const int* __restrict__ dst, int* __restrict__ deg, int E)
{
    int e = blockIdx.x * 256 + threadIdx.x;
    if (e < E) atomicAdd(&deg[dst[e]], 1);
}

__global__ __launch_bounds__(1024) void scan_kernel(
    const int* __restrict__ deg, int* __restrict__ rptr, int* __restrict__ cur, int n)
{
    __shared__ int sums[1024];
    int tid = threadIdx.x;
    int seg = (n + 1023) / 1024;
    int s0 = tid * seg;
    int s1 = min(s0 + seg, n);
    int local = 0;
    for (int i = s0; i < s1; ++i) local += deg[i];
    sums[tid] = local;
    __syncthreads();
    for (int o = 1; o < 1024; o <<= 1) {
        int t = (tid >= o) ? sums[tid - o] : 0;
        __syncthreads();
        sums[tid] += t;
        __syncthreads();
    }
    int run = sums[tid] - local;   // exclusive prefix of this segment
    for (int i = s0; i < s1; ++i) {
        rptr[i] = run; cur[i] = run;
        run += deg[i];
    }
    if (tid == 1023) rptr[n] = sums[1023];
}

__global__ void edge_fill(const int* __restrict__ src_idx, const int* __restrict__ dst_idx,
                          int* __restrict__ cur, int* __restrict__ csr_s, int E)
{
    int e = blockIdx.x * 256 + threadIdx.x;
    if (e >= E) return;
    int d = dst_idx[e];
    int slot = atomicAdd(&cur[d], 1);
    csr_s[slot] = src_idx[e];
}

// ---------------- per-dst gather: out[d,c] = (sum_j w_j * h[s_j,c]) / (sum_j w_j) ----
__global__ __launch_bounds__(128) void gather_out(
    const float* __restrict__ h, const float* __restrict__ el, const float* __restrict__ er,
    const int* __restrict__ rptr, const int* __restrict__ csr_s,
    float* __restrict__ out, int ndst)
{
    int d = blockIdx.x;
    if (d >= ndst) return;
    int c = threadIdx.x;        // 0..127
    int head = c >> 5;
    int j0 = rptr[d], j1 = rptr[d + 1];
    float erv = er[d * NH + head];
    float sum = 0.f, acc = 0.f;
    for (int j = j0; j < j1; ++j) {
        int s = csr_s[j];
        float e = el[s * NH + head] + erv;
        e = (e >= 0.f) ? e : NEG_SLOPE * e;
        float w0 = __expf(e);
        sum += w0;
        acc += w0 * h[(size_t)s * HD + c];
    }
    float inv = (j1 > j0) ? 1.f / sum : 0.f;
    out[(size_t)d * HD + c] = acc * inv;
}

// -----------------------------------------------------------------------------------
extern "C" void kernel_launch(void* const* d_in, const int* in_sizes, int n_in,
                              void* d_out, int out_size, void* d_ws, size_t ws_size,
                              hipStream_t stream)
{
    const float* x   = (const float*)d_in[0];
    const float* fw  = (const float*)d_in[1];
    const float* al  = (const float*)d_in[2];
    const float* ar  = (const float*)d_in[3];
    const int*   src = (const int*)d_in[4];
    const int*   dst = (const int*)d_in[5];
    const int*   dnid= (const int*)d_in[6];
    float* out = (float*)d_out;

    char* ws = (char*)d_ws;
    size_t off = 0;
    auto alloc = [&](size_t bytes) -> void* {
        void* p = ws + off;
        off = (off + bytes + 255) & ~(size_t)255;
        return p;
    };
    float* h    = (float*)alloc((size_t)N_SRC_N * HD * sizeof(float));   // 51.2 MB
    float* el   = (float*)alloc((size_t)N_SRC_N * NH * sizeof(float));   // 1.6 MB
    float* er   = (float*)alloc((size_t)N_DST_N * NH * sizeof(float));   // 0.8 MB
    int*   deg  = (int*)alloc((size_t)N_DST_N * sizeof(int));
    int*   rptr = (int*)alloc((size_t)(N_DST_N + 1) * sizeof(int));
    int*   cur  = (int*)alloc((size_t)N_DST_N * sizeof(int));
    int*   csr_s= (int*)alloc((size_t)NE * sizeof(int));                 // 4 MB

    hipMemsetAsync(deg, 0, (size_t)N_DST_N * sizeof(int), stream);

    gemm_fc<<<(N_SRC_N + BM - 1) / BM, 256, 0, stream>>>(x, fw, h, N_SRC_N);
    attn_scalars<<<(N_SRC_N + N_DST_N + 1) / 2, 256, 0, stream>>>(h, al, ar, dnid, el, er,
                                                                  N_SRC_N, N_DST_N);
    hist_kernel<<<(NE + 255) / 256, 256, 0, stream>>>(dst, deg, NE);
    scan_kernel<<<1, 1024, 0, stream>>>(deg, rptr, cur, N_DST_N);
    edge_fill<<<(NE + 255) / 256, 256, 0, stream>>>(src, dst, cur, csr_s, NE);
    gather_out<<<N_DST_N, 128, 0, stream>>>(h, el, er, rptr, csr_s, out, N_DST_N);
}

// Round 2
// 356.009 us; speedup vs baseline: 1.3019x; 1.3019x over previous
//
#include <hip/hip_runtime.h>
#include <hip/hip_bf16.h>

#define N_SRC_N  100000
#define N_DST_N  50000
#define NE       1000000
#define IN_F     256
#define NH       4
#define ND       32
#define HD       128   // NH*ND
#define NEG_SLOPE 0.2f

typedef __attribute__((ext_vector_type(8))) short short8v;
typedef __attribute__((ext_vector_type(4))) short short4v;
typedef __attribute__((ext_vector_type(4))) float f32x4;

__device__ __forceinline__ short f2bf(float f) {
    __hip_bfloat16 h = __float2bfloat16(f);   // RNE; compiler picks good codegen (m240)
    return *reinterpret_cast<short*>(&h);
}
__device__ __forceinline__ float bflo(unsigned u) { return __uint_as_float(u << 16); }
__device__ __forceinline__ float bfhi(unsigned u) { return __uint_as_float(u & 0xffff0000u); }

// ---------------- convert fc_w fp32 -> bf16 (64KB, stays L2-hot for the GEMM) -------
__global__ __launch_bounds__(256) void cvt_w(const float* __restrict__ w,
                                             short* __restrict__ wb)
{
    int i4 = blockIdx.x * 256 + threadIdx.x;          // over 8192 float4s (32768 elems)
    if (i4 < (HD * IN_F) / 4) {
        f32x4 v = ((const f32x4*)w)[i4];
        short4v s;
        s[0] = f2bf(v[0]); s[1] = f2bf(v[1]); s[2] = f2bf(v[2]); s[3] = f2bf(v[3]);
        ((short4v*)wb)[i4] = s;
    }
}

// ---------------- MFMA GEMM: hb = bf16(x @ w^T), el fused from fp32 acc -------------
// wave = 16 rows x 128 cols; block = 4 waves = 64 rows. A-frag from global fp32
// (coalesced: 16 rows x 32B contiguous segments), B-frag from global bf16 w (L1/L2).
__global__ __launch_bounds__(256) void gemm_fc_mfma(
    const float* __restrict__ x, const short* __restrict__ wb,
    const float* __restrict__ al, short* __restrict__ hb,
    float* __restrict__ el, int nrows)
{
    const int wid = threadIdx.x >> 6;
    const int l   = threadIdx.x & 63;
    const int lr  = l & 15;     // A: row-in-tile, B: col-in-tile, C: col
    const int lk  = l >> 4;     // k-group of 8; C: row-group of 4
    const int row0 = blockIdx.x * 64 + wid * 16;

    f32x4 acc[8];
#pragma unroll
    for (int t = 0; t < 8; ++t) acc[t] = (f32x4){0.f, 0.f, 0.f, 0.f};

    int arow = row0 + lr; if (arow > nrows - 1) arow = nrows - 1;  // clamp (pad rows)
    const float* xp = x + (size_t)arow * IN_F + lk * 8;
    const short* wp = wb + (size_t)lr * IN_F + lk * 8;

#pragma unroll
    for (int k0 = 0; k0 < IN_F; k0 += 32) {
        f32x4 a0 = *(const f32x4*)(xp + k0);
        f32x4 a1 = *(const f32x4*)(xp + k0 + 4);
        short8v af;
        af[0] = f2bf(a0[0]); af[1] = f2bf(a0[1]); af[2] = f2bf(a0[2]); af[3] = f2bf(a0[3]);
        af[4] = f2bf(a1[0]); af[5] = f2bf(a1[1]); af[6] = f2bf(a1[2]); af[7] = f2bf(a1[3]);
#pragma unroll
        for (int t = 0; t < 8; ++t) {
            short8v bf = *(const short8v*)(wp + (size_t)t * 16 * IN_F + k0);
            acc[t] = __builtin_amdgcn_mfma_f32_16x16x32_bf16(af, bf, acc[t], 0, 0, 0);
        }
    }

    // store h as bf16: row = row0 + lk*4 + r, col = t*16 + lr
#pragma unroll
    for (int r = 0; r < 4; ++r) {
        int row = row0 + lk * 4 + r;
        if (row < nrows) {
            short* hp = hb + (size_t)row * HD + lr;
#pragma unroll
            for (int t = 0; t < 8; ++t) hp[t * 16] = f2bf(acc[t][r]);
        }
    }

    // el[row, head] = sum_d h[row, head*32+d] * al[head*32+d], from fp32 acc.
    float alv[8];
#pragma unroll
    for (int t = 0; t < 8; ++t) alv[t] = al[t * 16 + lr];
#pragma unroll
    for (int hh = 0; hh < 4; ++hh) {
        float p[4];
#pragma unroll
        for (int r = 0; r < 4; ++r)
            p[r] = acc[2 * hh][r] * alv[2 * hh] + acc[2 * hh + 1][r] * alv[2 * hh + 1];
#pragma unroll
        for (int o = 1; o < 16; o <<= 1) {
#pragma unroll
            for (int r = 0; r < 4; ++r) p[r] += __shfl_xor(p[r], o, 64);
        }
        if (lr == 0) {
#pragma unroll
            for (int r = 0; r < 4; ++r) {
                int row = row0 + lk * 4 + r;
                if (row < nrows) el[row * NH + hh] = p[r];
            }
        }
    }
}

// ---------------- er[i,head] = <hb[dnid[i]], ar> per head; wave per i ---------------
__global__ __launch_bounds__(256) void er_kernel(
    const short* __restrict__ hb, const float* __restrict__ ar,
    const int* __restrict__ dnid, float* __restrict__ er, int ndst)
{
    int i = blockIdx.x * 4 + (threadIdx.x >> 6);
    if (i >= ndst) return;
    int l = threadIdx.x & 63;
    int n = dnid[i];
    unsigned u = *(const unsigned*)(hb + (size_t)n * HD + 2 * l);
    float s = bflo(u) * ar[2 * l] + bfhi(u) * ar[2 * l + 1];
#pragma unroll
    for (int o = 1; o < 16; o <<= 1) s += __shfl_xor(s, o, 64);
    if ((l & 15) == 0) er[i * NH + (l >> 4)] = s;
}

// ---------------- CSR build --------------------------------------------------------
__global__ void hist_kernel(const int4* __restrict__ dst4, int* __restrict__ deg, int n4)
{
    int e = blockIdx.x * 256 + threadIdx.x;
    if (e < n4) {
        int4 v = dst4[e];
        atomicAdd(&deg[v.x], 1); atomicAdd(&deg[v.y], 1);
        atomicAdd(&deg[v.z], 1); atomicAdd(&deg[v.w], 1);
    }
}

__global__ __launch_bounds__(1024) void scan_kernel(
    const int* __restrict__ deg, int* __restrict__ rptr, int* __restrict__ cur, int n)
{
    __shared__ int sums[1024];
    int tid = threadIdx.x;
    int seg = (n + 1023) / 1024;
    int s0 = tid * seg;
    int s1 = min(s0 + seg, n);
    int local = 0;
    for (int i = s0; i < s1; ++i) local += deg[i];
    sums[tid] = local;
    __syncthreads();
    for (int o = 1; o < 1024; o <<= 1) {
        int t = (tid >= o) ? sums[tid - o] : 0;
        __syncthreads();
        sums[tid] += t;
        __syncthreads();
    }
    int run = sums[tid] - local;
    for (int i = s0; i < s1; ++i) {
        rptr[i] = run; cur[i] = run;
        run += deg[i];
    }
    if (tid == 1023) rptr[n] = sums[1023];
}

__global__ void edge_fill(const int4* __restrict__ src4, const int4* __restrict__ dst4,
                          int* __restrict__ cur, int* __restrict__ csr_s, int n4)
{
    int e = blockIdx.x * 256 + threadIdx.x;
    if (e >= n4) return;
    int4 s = src4[e];
    int4 d = dst4[e];
    csr_s[atomicAdd(&cur[d.x], 1)] = s.x;
    csr_s[atomicAdd(&cur[d.y], 1)] = s.y;
    csr_s[atomicAdd(&cur[d.z], 1)] = s.z;
    csr_s[atomicAdd(&cur[d.w], 1)] = s.w;
}

// ---- per-dst gather: out[d,c] = (sum_j w_j * h[s_j,c]) / (sum_j w_j); wave per d ----
__global__ __launch_bounds__(256) void gather_out(
    const short* __restrict__ hb, const float* __restrict__ el,
    const float* __restrict__ er, const int* __restrict__ rptr,
    const int* __restrict__ csr_s, float* __restrict__ out, int ndst)
{
    int d = blockIdx.x * 4 + (threadIdx.x >> 6);
    if (d >= ndst) return;
    int l = threadIdx.x & 63;
    int head = l >> 4;                       // cols 2l,2l+1 are in head (2l)>>5 = l>>4
    int j0 = rptr[d], j1 = rptr[d + 1];
    float erv = er[d * NH + head];

    float sumA = 0.f, sumB = 0.f;
    float acc0A = 0.f, acc1A = 0.f, acc0B = 0.f, acc1B = 0.f;
    int j = j0;
    for (; j + 2 <= j1; j += 2) {            // 2-edge unroll: two independent chains
        int s0 = csr_s[j], s1 = csr_s[j + 1];
        unsigned u0 = *(const unsigned*)(hb + (size_t)s0 * HD + 2 * l);
        unsigned u1 = *(const unsigned*)(hb + (size_t)s1 * HD + 2 * l);
        float e0 = el[s0 * NH + head] + erv;
        float e1 = el[s1 * NH + head] + erv;
        e0 = (e0 >= 0.f) ? e0 : NEG_SLOPE * e0;
        e1 = (e1 >= 0.f) ? e1 : NEG_SLOPE * e1;
        float w0 = __expf(e0), w1 = __expf(e1);
        sumA += w0; sumB += w1;
        acc0A = fmaf(w0, bflo(u0), acc0A); acc1A = fmaf(w0, bfhi(u0), acc1A);
        acc0B = fmaf(w1, bflo(u1), acc0B); acc1B = fmaf(w1, bfhi(u1), acc1B);
    }
    if (j < j1) {
        int s0 = csr_s[j];
        unsigned u0 = *(const unsigned*)(hb + (size_t)s0 * HD + 2 * l);
        float e0 = el[s0 * NH + head] + erv;
        e0 = (e0 >= 0.f) ? e0 : NEG_SLOPE * e0;
        float w0 = __expf(e0);
        sumA += w0;
        acc0A = fmaf(w0, bflo(u0), acc0A); acc1A = fmaf(w0, bfhi(u0), acc1A);
    }
    float sum = sumA + sumB;
    float a0 = acc0A + acc0B, a1 = acc1A + acc1B;
    float inv = (j1 > j0) ? 1.f / sum : 0.f;
    float2 o2 = make_float2(a0 * inv, a1 * inv);
    *(float2*)(out + (size_t)d * HD + 2 * l) = o2;
}

// -----------------------------------------------------------------------------------
extern "C" void kernel_launch(void* const* d_in, const int* in_sizes, int n_in,
                              void* d_out, int out_size, void* d_ws, size_t ws_size,
                              hipStream_t stream)
{
    const float* x   = (const float*)d_in[0];
    const float* fw  = (const float*)d_in[1];
    const float* al  = (const float*)d_in[2];
    const float* ar  = (const float*)d_in[3];
    const int*   src = (const int*)d_in[4];
    const int*   dst = (const int*)d_in[5];
    const int*   dnid= (const int*)d_in[6];
    float* out = (float*)d_out;

    char* ws = (char*)d_ws;
    size_t off = 0;
    auto alloc = [&](size_t bytes) -> void* {
        void* p = ws + off;
        off = (off + bytes + 255) & ~(size_t)255;
        return p;
    };
    short* hb   = (short*)alloc((size_t)N_SRC_N * HD * sizeof(short));   // 25.6 MB
    short* wb   = (short*)alloc((size_t)HD * IN_F * sizeof(short));      // 64 KB
    float* el   = (float*)alloc((size_t)N_SRC_N * NH * sizeof(float));   // 1.6 MB
    float* er   = (float*)alloc((size_t)N_DST_N * NH * sizeof(float));   // 0.8 MB
    int*   deg  = (int*)alloc((size_t)N_DST_N * sizeof(int));
    int*   rptr = (int*)alloc((size_t)(N_DST_N + 1) * sizeof(int));
    int*   cur  = (int*)alloc((size_t)N_DST_N * sizeof(int));
    int*   csr_s= (int*)alloc((size_t)NE * sizeof(int));                 // 4 MB

    hipMemsetAsync(deg, 0, (size_t)N_DST_N * sizeof(int), stream);

    cvt_w<<<(HD * IN_F / 4 + 255) / 256, 256, 0, stream>>>(fw, wb);
    gemm_fc_mfma<<<(N_SRC_N + 63) / 64, 256, 0, stream>>>(x, wb, al, hb, el, N_SRC_N);
    er_kernel<<<(N_DST_N + 3) / 4, 256, 0, stream>>>(hb, ar, dnid, er, N_DST_N);
    hist_kernel<<<(NE / 4 + 255) / 256, 256, 0, stream>>>((const int4*)dst, deg, NE / 4);
    scan_kernel<<<1, 1024, 0, stream>>>(deg, rptr, cur, N_DST_N);
    edge_fill<<<(NE / 4 + 255) / 256, 256, 0, stream>>>((const int4*)src, (const int4*)dst,
                                                        cur, csr_s, NE / 4);
    gather_out<<<(N_DST_N + 3) / 4, 256, 0, stream>>>(hb, el, er, rptr, csr_s, out, N_DST_N);
}

// Round 3
// 270.239 us; speedup vs baseline: 1.7152x; 1.3174x over previous
//
#include <hip/hip_runtime.h>
#include <hip/hip_bf16.h>

#define N_SRC_N  100000
#define N_DST_N  50000
#define NE       1000000
#define IN_F     256
#define NH       4
#define ND       32
#define HD       128   // NH*ND
#define NEG_SLOPE 0.2f

typedef __attribute__((ext_vector_type(8))) short short8v;
typedef __attribute__((ext_vector_type(4))) short short4v;
typedef __attribute__((ext_vector_type(4))) float f32x4;

__device__ __forceinline__ short f2bf(float f) {
    __hip_bfloat16 h = __float2bfloat16(f);
    return *reinterpret_cast<short*>(&h);
}
__device__ __forceinline__ float bflo(unsigned u) { return __uint_as_float(u << 16); }
__device__ __forceinline__ float bfhi(unsigned u) { return __uint_as_float(u & 0xffff0000u); }

// ---------------- convert fc_w fp32 -> bf16 (64KB, stays L2-hot for the GEMM) -------
__global__ __launch_bounds__(256) void cvt_w(const float* __restrict__ w,
                                             short* __restrict__ wb)
{
    int i4 = blockIdx.x * 256 + threadIdx.x;
    if (i4 < (HD * IN_F) / 4) {
        f32x4 v = ((const f32x4*)w)[i4];
        short4v s;
        s[0] = f2bf(v[0]); s[1] = f2bf(v[1]); s[2] = f2bf(v[2]); s[3] = f2bf(v[3]);
        ((short4v*)wb)[i4] = s;
    }
}

// ---------------- MFMA GEMM: hb = bf16(x @ w^T), el fused from fp32 acc -------------
__global__ __launch_bounds__(256) void gemm_fc_mfma(
    const float* __restrict__ x, const short* __restrict__ wb,
    const float* __restrict__ al, short* __restrict__ hb,
    float* __restrict__ el, int nrows)
{
    const int wid = threadIdx.x >> 6;
    const int l   = threadIdx.x & 63;
    const int lr  = l & 15;
    const int lk  = l >> 4;
    const int row0 = blockIdx.x * 64 + wid * 16;

    f32x4 acc[8];
#pragma unroll
    for (int t = 0; t < 8; ++t) acc[t] = (f32x4){0.f, 0.f, 0.f, 0.f};

    int arow = row0 + lr; if (arow > nrows - 1) arow = nrows - 1;
    const float* xp = x + (size_t)arow * IN_F + lk * 8;
    const short* wp = wb + (size_t)lr * IN_F + lk * 8;

#pragma unroll
    for (int k0 = 0; k0 < IN_F; k0 += 32) {
        f32x4 a0 = *(const f32x4*)(xp + k0);
        f32x4 a1 = *(const f32x4*)(xp + k0 + 4);
        short8v af;
        af[0] = f2bf(a0[0]); af[1] = f2bf(a0[1]); af[2] = f2bf(a0[2]); af[3] = f2bf(a0[3]);
        af[4] = f2bf(a1[0]); af[5] = f2bf(a1[1]); af[6] = f2bf(a1[2]); af[7] = f2bf(a1[3]);
#pragma unroll
        for (int t = 0; t < 8; ++t) {
            short8v bf = *(const short8v*)(wp + (size_t)t * 16 * IN_F + k0);
            acc[t] = __builtin_amdgcn_mfma_f32_16x16x32_bf16(af, bf, acc[t], 0, 0, 0);
        }
    }

#pragma unroll
    for (int r = 0; r < 4; ++r) {
        int row = row0 + lk * 4 + r;
        if (row < nrows) {
            short* hp = hb + (size_t)row * HD + lr;
#pragma unroll
            for (int t = 0; t < 8; ++t) hp[t * 16] = f2bf(acc[t][r]);
        }
    }

    float alv[8];
#pragma unroll
    for (int t = 0; t < 8; ++t) alv[t] = al[t * 16 + lr];
#pragma unroll
    for (int hh = 0; hh < 4; ++hh) {
        float p[4];
#pragma unroll
        for (int r = 0; r < 4; ++r)
            p[r] = acc[2 * hh][r] * alv[2 * hh] + acc[2 * hh + 1][r] * alv[2 * hh + 1];
#pragma unroll
        for (int o = 1; o < 16; o <<= 1) {
#pragma unroll
            for (int r = 0; r < 4; ++r) p[r] += __shfl_xor(p[r], o, 64);
        }
        if (lr == 0) {
#pragma unroll
            for (int r = 0; r < 4; ++r) {
                int row = row0 + lk * 4 + r;
                if (row < nrows) el[row * NH + hh] = p[r];
            }
        }
    }
}

// ---------------- er[i,head] = <hb[dnid[i]], ar> per head; wave per i ---------------
__global__ __launch_bounds__(256) void er_kernel(
    const short* __restrict__ hb, const float* __restrict__ ar,
    const int* __restrict__ dnid, float* __restrict__ er, int ndst)
{
    int i = blockIdx.x * 4 + (threadIdx.x >> 6);
    if (i >= ndst) return;
    int l = threadIdx.x & 63;
    int n = dnid[i];
    unsigned u = *(const unsigned*)(hb + (size_t)n * HD + 2 * l);
    float s = bflo(u) * ar[2 * l] + bfhi(u) * ar[2 * l + 1];
#pragma unroll
    for (int o = 1; o < 16; o <<= 1) s += __shfl_xor(s, o, 64);
    if ((l & 15) == 0) er[i * NH + (l >> 4)] = s;
}

// ---------------- CSR build --------------------------------------------------------
__global__ void hist_kernel(const int4* __restrict__ dst4, int* __restrict__ deg, int n4)
{
    int e = blockIdx.x * 256 + threadIdx.x;
    if (e < n4) {
        int4 v = dst4[e];
        atomicAdd(&deg[v.x], 1); atomicAdd(&deg[v.y], 1);
        atomicAdd(&deg[v.z], 1); atomicAdd(&deg[v.w], 1);
    }
}

// -------- 3-kernel device scan over deg[0..n) (replaces 110us single-block scan) ----
__global__ __launch_bounds__(256) void reduce_blocks(
    const int* __restrict__ deg, int* __restrict__ bsum, int n)
{
    int idx = blockIdx.x * 256 + threadIdx.x;
    int v = (idx < n) ? deg[idx] : 0;
#pragma unroll
    for (int o = 1; o < 64; o <<= 1) v += __shfl_xor(v, o, 64);
    __shared__ int s[4];
    if ((threadIdx.x & 63) == 0) s[threadIdx.x >> 6] = v;
    __syncthreads();
    if (threadIdx.x == 0) bsum[blockIdx.x] = s[0] + s[1] + s[2] + s[3];
}

__global__ __launch_bounds__(256) void scan_bsum(
    const int* __restrict__ bsum, int* __restrict__ boff,
    int* __restrict__ rptr_total, int nblk)
{
    int tid = threadIdx.x;
    int v = (tid < nblk) ? bsum[tid] : 0;
    int orig = v;
#pragma unroll
    for (int o = 1; o < 64; o <<= 1) {
        int t = __shfl_up(v, o, 64);
        if ((tid & 63) >= o) v += t;
    }
    __shared__ int ws[4];
    if ((tid & 63) == 63) ws[tid >> 6] = v;
    __syncthreads();
    int add = 0;
    for (int w = 0; w < (tid >> 6); ++w) add += ws[w];
    v += add;
    if (tid < nblk) boff[tid] = v - orig;
    if (tid == nblk - 1) rptr_total[0] = v;    // = rptr[n]
}

__global__ __launch_bounds__(256) void scan_write(
    const int* __restrict__ deg, const int* __restrict__ boff,
    int* __restrict__ rptr, int* __restrict__ cur, int n)
{
    int tid = threadIdx.x;
    int idx = blockIdx.x * 256 + tid;
    int v = (idx < n) ? deg[idx] : 0;
    int orig = v;
#pragma unroll
    for (int o = 1; o < 64; o <<= 1) {
        int t = __shfl_up(v, o, 64);
        if ((tid & 63) >= o) v += t;
    }
    __shared__ int ws[4];
    if ((tid & 63) == 63) ws[tid >> 6] = v;
    __syncthreads();
    int add = boff[blockIdx.x];
    for (int w = 0; w < (tid >> 6); ++w) add += ws[w];
    int excl = v - orig + add;
    if (idx < n) { rptr[idx] = excl; cur[idx] = excl; }
}

__global__ void edge_fill(const int4* __restrict__ src4, const int4* __restrict__ dst4,
                          int* __restrict__ cur, int* __restrict__ csr_s, int n4)
{
    int e = blockIdx.x * 256 + threadIdx.x;
    if (e >= n4) return;
    int4 s = src4[e];
    int4 d = dst4[e];
    csr_s[atomicAdd(&cur[d.x], 1)] = s.x;
    csr_s[atomicAdd(&cur[d.y], 1)] = s.y;
    csr_s[atomicAdd(&cur[d.z], 1)] = s.z;
    csr_s[atomicAdd(&cur[d.w], 1)] = s.w;
}

// ---- per-dst gather: out[d,c] = (sum_j w_j * h[s_j,c]) / (sum_j w_j); wave per d ----
__global__ __launch_bounds__(256) void gather_out(
    const short* __restrict__ hb, const float* __restrict__ el,
    const float* __restrict__ er, const int* __restrict__ rptr,
    const int* __restrict__ csr_s, float* __restrict__ out, int ndst)
{
    int d = blockIdx.x * 4 + (threadIdx.x >> 6);
    if (d >= ndst) return;
    int l = threadIdx.x & 63;
    int head = l >> 4;
    int j0 = rptr[d], j1 = rptr[d + 1];
    float erv = er[d * NH + head];

    float sumA = 0.f, sumB = 0.f;
    float acc0A = 0.f, acc1A = 0.f, acc0B = 0.f, acc1B = 0.f;
    int j = j0;
    for (; j + 2 <= j1; j += 2) {
        int s0 = csr_s[j], s1 = csr_s[j + 1];
        unsigned u0 = *(const unsigned*)(hb + (size_t)s0 * HD + 2 * l);
        unsigned u1 = *(const unsigned*)(hb + (size_t)s1 * HD + 2 * l);
        float e0 = el[s0 * NH + head] + erv;
        float e1 = el[s1 * NH + head] + erv;
        e0 = (e0 >= 0.f) ? e0 : NEG_SLOPE * e0;
        e1 = (e1 >= 0.f) ? e1 : NEG_SLOPE * e1;
        float w0 = __expf(e0), w1 = __expf(e1);
        sumA += w0; sumB += w1;
        acc0A = fmaf(w0, bflo(u0), acc0A); acc1A = fmaf(w0, bfhi(u0), acc1A);
        acc0B = fmaf(w1, bflo(u1), acc0B); acc1B = fmaf(w1, bfhi(u1), acc1B);
    }
    if (j < j1) {
        int s0 = csr_s[j];
        unsigned u0 = *(const unsigned*)(hb + (size_t)s0 * HD + 2 * l);
        float e0 = el[s0 * NH + head] + erv;
        e0 = (e0 >= 0.f) ? e0 : NEG_SLOPE * e0;
        float w0 = __expf(e0);
        sumA += w0;
        acc0A = fmaf(w0, bflo(u0), acc0A); acc1A = fmaf(w0, bfhi(u0), acc1A);
    }
    float sum = sumA + sumB;
    float a0 = acc0A + acc0B, a1 = acc1A + acc1B;
    float inv = (j1 > j0) ? 1.f / sum : 0.f;
    float2 o2 = make_float2(a0 * inv, a1 * inv);
    *(float2*)(out + (size_t)d * HD + 2 * l) = o2;
}

// -----------------------------------------------------------------------------------
extern "C" void kernel_launch(void* const* d_in, const int* in_sizes, int n_in,
                              void* d_out, int out_size, void* d_ws, size_t ws_size,
                              hipStream_t stream)
{
    const float* x   = (const float*)d_in[0];
    const float* fw  = (const float*)d_in[1];
    const float* al  = (const float*)d_in[2];
    const float* ar  = (const float*)d_in[3];
    const int*   src = (const int*)d_in[4];
    const int*   dst = (const int*)d_in[5];
    const int*   dnid= (const int*)d_in[6];
    float* out = (float*)d_out;

    char* ws = (char*)d_ws;
    size_t off = 0;
    auto alloc = [&](size_t bytes) -> void* {
        void* p = ws + off;
        off = (off + bytes + 255) & ~(size_t)255;
        return p;
    };
    short* hb   = (short*)alloc((size_t)N_SRC_N * HD * sizeof(short));   // 25.6 MB
    short* wb   = (short*)alloc((size_t)HD * IN_F * sizeof(short));      // 64 KB
    float* el   = (float*)alloc((size_t)N_SRC_N * NH * sizeof(float));   // 1.6 MB
    float* er   = (float*)alloc((size_t)N_DST_N * NH * sizeof(float));   // 0.8 MB
    int*   deg  = (int*)alloc((size_t)N_DST_N * sizeof(int));
    int*   rptr = (int*)alloc((size_t)(N_DST_N + 1) * sizeof(int));
    int*   cur  = (int*)alloc((size_t)N_DST_N * sizeof(int));
    int*   csr_s= (int*)alloc((size_t)NE * sizeof(int));                 // 4 MB
    const int NBLK = (N_DST_N + 255) / 256;                              // 196
    int*   bsum = (int*)alloc((size_t)NBLK * sizeof(int));
    int*   boff = (int*)alloc((size_t)NBLK * sizeof(int));

    hipMemsetAsync(deg, 0, (size_t)N_DST_N * sizeof(int), stream);

    cvt_w<<<(HD * IN_F / 4 + 255) / 256, 256, 0, stream>>>(fw, wb);
    gemm_fc_mfma<<<(N_SRC_N + 63) / 64, 256, 0, stream>>>(x, wb, al, hb, el, N_SRC_N);
    er_kernel<<<(N_DST_N + 3) / 4, 256, 0, stream>>>(hb, ar, dnid, er, N_DST_N);
    hist_kernel<<<(NE / 4 + 255) / 256, 256, 0, stream>>>((const int4*)dst, deg, NE / 4);
    reduce_blocks<<<NBLK, 256, 0, stream>>>(deg, bsum, N_DST_N);
    scan_bsum<<<1, 256, 0, stream>>>(bsum, boff, rptr + N_DST_N, NBLK);
    scan_write<<<NBLK, 256, 0, stream>>>(deg, boff, rptr, cur, N_DST_N);
    edge_fill<<<(NE / 4 + 255) / 256, 256, 0, stream>>>((const int4*)src, (const int4*)dst,
                                                        cur, csr_s, NE / 4);
    gather_out<<<(N_DST_N + 3) / 4, 256, 0, stream>>>(hb, el, er, rptr, csr_s, out, N_DST_N);
}